// Round 16
// baseline (1158.194 us; speedup 1.0000x reference)
//
#include <hip/hip_runtime.h>

#define DIM 1024
#define HID 1536
#define TT 4096
#define NB 4
#define KCONV 4
#define MROWS (NB * TT)  // 16384
#define NC 256           // scan chunks
#define CH (TT / NC)     // 16
#define H8 (HID / 8)     // 192
#define H4 (HID / 4)     // 384
#define TC 16            // conv rows per thread

typedef unsigned short u16;
typedef short bf16x8 __attribute__((ext_vector_type(8)));
typedef u16 u16x4 __attribute__((ext_vector_type(4)));
typedef float f32x4 __attribute__((ext_vector_type(4)));

__device__ __forceinline__ u16 f2bf(float f) {
  union { float f; unsigned u; } v; v.f = f;
  unsigned r = (v.u + 0x7fffu + ((v.u >> 16) & 1u)) >> 16;
  return (u16)r;
}
__device__ __forceinline__ float bf2f(u16 h) {
  union { unsigned u; float f; } v; v.u = ((unsigned)h) << 16;
  return v.f;
}
__device__ __forceinline__ float gelu_exact(float g) {
  return 0.5f * g * (1.0f + erff(g * 0.70710678118f));
}

// ---------------- fused fp32 -> bf16 convert (4 regions, 1 launch) --------
__global__ void cvt_all(const float* __restrict__ s0, u16* __restrict__ d0, int n0,
                        const float* __restrict__ s1, u16* __restrict__ d1, int n1,
                        const float* __restrict__ s2, u16* __restrict__ d2, int n2,
                        const float* __restrict__ s3, u16* __restrict__ d3, int n3) {
  int i = blockIdx.x * blockDim.x + threadIdx.x;  // in float4 units
  const float* s; u16* d; int k;
  if (i < n0) { s = s0; d = d0; k = i; }
  else if (i < n0 + n1) { s = s1; d = d1; k = i - n0; }
  else if (i < n0 + n1 + n2) { s = s2; d = d2; k = i - n0 - n1; }
  else if (i < n0 + n1 + n2 + n3) { s = s3; d = d3; k = i - n0 - n1 - n2; }
  else return;
  float4 v = reinterpret_cast<const float4*>(s)[k];
  ushort4 o;
  o.x = f2bf(v.x); o.y = f2bf(v.y); o.z = f2bf(v.z); o.w = f2bf(v.w);
  reinterpret_cast<ushort4*>(d)[k] = o;
}

#define AS1q __attribute__((address_space(1)))
#define AS3q __attribute__((address_space(3)))
__device__ __forceinline__ void glds16(const u16* g, u16* l) {
  __builtin_amdgcn_global_load_lds((const AS1q void*)g, (AS3q void*)l, 16, 0, 0);
}

// ================= 256x256 bf16 NT GEMM, 4-phase/iter =====================
// R15 (verified +6.5%): pre-MFMA barriers removed; sched_barrier(0) pins
// stage-before-MFMA. R16: uniform WAITV8 at each phase end — every read's
// producer-stage is exactly 3 phase-groups old; vmcnt(8) leaves only the 2
// newest groups outstanding => producer complete, and each stage now gets a
// 2-phase (~1200cy) window to cover ~900cy HBM latency (R15's WAITV4 at P2
// forced a 1-phase lead => ~300cy stall). Last iter: conservative tight path.
#define BAR    asm volatile("s_barrier" ::: "memory")
#define WAITV8 asm volatile("s_waitcnt vmcnt(8)" ::: "memory")
#define WAITV4 asm volatile("s_waitcnt vmcnt(4)" ::: "memory")
#define WAITV0 asm volatile("s_waitcnt vmcnt(0)" ::: "memory")
#define SCHED0 __builtin_amdgcn_sched_barrier(0)

template <int EPI>
__global__ __launch_bounds__(512, 2) void gemm256(
    const u16* __restrict__ A, const u16* __restrict__ B,
    float* __restrict__ C, u16* __restrict__ O0, u16* __restrict__ O1,
    int M, int Nn, int K, int gx) {
  __shared__ u16 LA[2][2][8192];
  __shared__ u16 LB[2][2][8192];
  const int tid = threadIdx.x;
  const int l = tid & 63;
  const int wid = tid >> 6;
  const int wr = wid >> 2;
  const int wc = wid & 3;

  // two-level XCD swizzle (R6-verified: FETCH 227->123 MB)
  const int bid = blockIdx.x;
  const int gm8 = (M >> 8) >> 3;
  const int xcd = bid & 7;
  const int idx = bid >> 3;
  const int mg  = idx / (4 * gx);
  const int rem = idx % (4 * gx);
  const int nn  = rem >> 2;
  const int mi  = rem & 3;
  const int tileM = (xcd * gm8 + mg * 4 + mi) * 256;
  const int tileN = nn * 256;

  const int lp = l ^ ((l & 32) >> 4);
  const int srow = lp >> 2;
  const int scol = (lp & 3) * 8;
  const int rdoff = ((l & 15) * 32 + (l >> 4) * 8) ^ ((l & 8) << 1);

  const u16* Abase = A + (size_t)(tileM + wid * 32 + srow) * K + scol;
  const u16* Bbase = B + (size_t)(tileN + wid * 32 + srow) * K + scol;

#define STAGE_A(c, kk, kt) { const u16* g_ = Abase + (size_t)(kt) * 64 + (kk) * 32; \
    glds16(g_, &LA[c][kk][wid * 1024]); glds16(g_ + 16 * (size_t)K, &LA[c][kk][wid * 1024 + 512]); }
#define STAGE_B(c, kk, kt) { const u16* g_ = Bbase + (size_t)(kt) * 64 + (kk) * 32; \
    glds16(g_, &LB[c][kk][wid * 1024]); glds16(g_ + 16 * (size_t)K, &LB[c][kk][wid * 1024 + 512]); }

  f32x4 acc[8][4] = {};
  bf16x8 a[8], b[4];

#define LDB4(c, kk) { _Pragma("unroll") for (int ni = 0; ni < 4; ni++) \
    b[ni] = *(const bf16x8*)&LB[c][kk][(wc * 4 + ni) * 512 + rdoff]; }
#define LDA8(c, kk) { _Pragma("unroll") for (int mi2 = 0; mi2 < 8; mi2++) \
    a[mi2] = *(const bf16x8*)&LA[c][kk][(wr * 8 + mi2) * 512 + rdoff]; }
#define MFMA32 { __builtin_amdgcn_s_setprio(1); \
    _Pragma("unroll") for (int mi2 = 0; mi2 < 8; mi2++) \
    _Pragma("unroll") for (int ni = 0; ni < 4; ni++) \
      acc[mi2][ni] = __builtin_amdgcn_mfma_f32_16x16x32_bf16(a[mi2], b[ni], acc[mi2][ni], 0, 0, 0); \
    __builtin_amdgcn_s_setprio(0); }

  STAGE_A(0, 0, 0); STAGE_B(0, 0, 0);
  STAGE_A(0, 1, 0); STAGE_B(0, 1, 0);
  STAGE_A(1, 0, 1); STAGE_B(1, 0, 1);
  WAITV4; BAR;

  const int NIT = K >> 7;
  for (int i = 0; i < NIT; i++) {
    const int kt = 2 * i;
    if (i + 1 < NIT) {
      // P1: read buf0/kk0; stage buf1/kk1(kt+1)
      LDB4(0, 0); LDA8(0, 0); STAGE_A(1, 1, kt + 1); STAGE_B(1, 1, kt + 1);
      SCHED0; MFMA32; WAITV8; BAR;
      // P2: read buf0/kk1; stage buf0/kk0(kt+2)
      LDB4(0, 1); LDA8(0, 1); STAGE_A(0, 0, kt + 2); STAGE_B(0, 0, kt + 2);
      SCHED0; MFMA32; WAITV8; BAR;
      // P3: read buf1/kk0; stage buf0/kk1(kt+2)
      LDB4(1, 0); LDA8(1, 0); STAGE_A(0, 1, kt + 2); STAGE_B(0, 1, kt + 2);
      SCHED0; MFMA32; WAITV8; BAR;
      // P4: read buf1/kk1; stage buf1/kk0(kt+3)
      LDB4(1, 1); LDA8(1, 1); STAGE_A(1, 0, kt + 3); STAGE_B(1, 0, kt + 3);
      SCHED0; MFMA32; WAITV8; BAR;
    } else {
      // last iter: only P1 stages (kt+1 is consumed by P3/P4 this iter)
      LDB4(0, 0); LDA8(0, 0); STAGE_A(1, 1, kt + 1); STAGE_B(1, 1, kt + 1);
      SCHED0; MFMA32; WAITV4; BAR;   // drains all prior-iter stages
      LDB4(0, 1); LDA8(0, 1);
      SCHED0; MFMA32; WAITV0; BAR;   // drains P1's stage before buf1 reads
      LDB4(1, 0); LDA8(1, 0);
      SCHED0; MFMA32; BAR;
      LDB4(1, 1); LDA8(1, 1);
      SCHED0; MFMA32; BAR;
    }
  }

  const int r0 = tileM + wr * 128 + (l >> 4) * 4;
  const int c0 = tileN + wc * 64 + (l & 15);
  if (EPI == 0) {
#pragma unroll
    for (int ai = 0; ai < 8; ai++)
#pragma unroll
      for (int ni = 0; ni < 4; ni++)
#pragma unroll
        for (int r = 0; r < 4; r++)
          C[(size_t)(r0 + ai * 16 + r) * Nn + (c0 + ni * 16)] = acc[ai][ni][r];
  } else {
    const bool lo = (tileN < HID);
    u16* dst = lo ? O0 : O1;
    const int cb = lo ? 0 : HID;
#pragma unroll
    for (int ai = 0; ai < 8; ai++)
#pragma unroll
      for (int ni = 0; ni < 4; ni++)
#pragma unroll
        for (int r = 0; r < 4; r++) {
          float v = acc[ai][ni][r];
          if (EPI == 2 && lo) v = gelu_exact(v);
          dst[(size_t)(r0 + ai * 16 + r) * HID + (c0 + ni * 16 - cb)] = f2bf(v);
        }
  }
#undef STAGE_A
#undef STAGE_B
#undef LDB4
#undef LDA8
#undef MFMA32
}

// ---------------- causal depthwise conv1d (K=4) ----------------
__global__ void conv1d_k(const u16* __restrict__ u, const float* __restrict__ w,
                         const float* __restrict__ b, u16* __restrict__ uc) {
  int idx = blockIdx.x * blockDim.x + threadIdx.x;  // NB*(TT/TC)*H8
  int hb = (idx % H8) * 8;
  int rc = idx / H8;
  int t0 = (rc % (TT / TC)) * TC;
  int n  = rc / (TT / TC);

  float wt[KCONV][8], bias[8];
#pragma unroll
  for (int j = 0; j < 8; j++) {
    float4 wj = reinterpret_cast<const float4*>(w)[hb + j];
    wt[0][j] = wj.x; wt[1][j] = wj.y; wt[2][j] = wj.z; wt[3][j] = wj.w;
    bias[j] = b[hb + j];
  }

  const u16* up = u + (size_t)n * TT * HID + hb;
  u16* op = uc + (size_t)n * TT * HID + hb;
  bf16x8 zero;
#pragma unroll
  for (int j = 0; j < 8; j++) zero[j] = 0;
  bf16x8 w0 = (t0 > 0) ? *(const bf16x8*)&up[(size_t)(t0 - 3) * HID] : zero;
  bf16x8 w1 = (t0 > 0) ? *(const bf16x8*)&up[(size_t)(t0 - 2) * HID] : zero;
  bf16x8 w2 = (t0 > 0) ? *(const bf16x8*)&up[(size_t)(t0 - 1) * HID] : zero;
#pragma unroll 4
  for (int t = t0; t < t0 + TC; t++) {
    bf16x8 cur = *(const bf16x8*)&up[(size_t)t * HID];
    bf16x8 o;
#pragma unroll
    for (int j = 0; j < 8; j++) {
      float a = bias[j];
      a += bf2f((u16)w0[j]) * wt[0][j];
      a += bf2f((u16)w1[j]) * wt[1][j];
      a += bf2f((u16)w2[j]) * wt[2][j];
      a += bf2f((u16)cur[j]) * wt[3][j];
      o[j] = (short)f2bf(a);
    }
    *(bf16x8*)&op[(size_t)t * HID] = o;
    w0 = w1; w1 = w2; w2 = cur;
  }
}

// ---------------- RG-LRU scan, chunked 3-phase, 4 ch/thread (R12) ----------
__global__ void scan_phase1(const u16* __restrict__ fbuf, const u16* __restrict__ ibuf,
                            const u16* __restrict__ ubuf, const float* __restrict__ fb,
                            const float* __restrict__ bg,
                            float* __restrict__ Ac, float* __restrict__ Bc) {
  int tid = blockIdx.x * blockDim.x + threadIdx.x;  // NB*H4*NC
  int hb = (tid % H4) * 4;
  int nc = tid / H4;
  int n = nc % NB;
  int c = nc / NB;
  f32x4 fbv = *reinterpret_cast<const f32x4*>(&fb[hb]);
  f32x4 bgf = *reinterpret_cast<const f32x4*>(&bg[hb]);
  f32x4 bgi = *reinterpret_cast<const f32x4*>(&bg[HID + hb]);
  float c8[4], ap[4] = {1.f, 1.f, 1.f, 1.f}, hl[4] = {0.f, 0.f, 0.f, 0.f};
#pragma unroll
  for (int j = 0; j < 4; j++) c8[j] = 8.0f * log1pf(expf(fbv[j]));
  size_t base = ((size_t)n * TT + (size_t)c * CH) * HID + hb;
  for (int t = 0; t < CH; t++) {
    size_t ix = base + (size_t)t * HID;
    u16x4 f4 = *reinterpret_cast<const u16x4*>(&fbuf[ix]);
    u16x4 i4 = *reinterpret_cast<const u16x4*>(&ibuf[ix]);
    u16x4 u4 = *reinterpret_cast<const u16x4*>(&ubuf[ix]);
#pragma unroll
    for (int j = 0; j < 4; j++) {
      float f = bf2f(f4[j]) + bgf[j];
      float sf = 1.0f / (1.0f + expf(-f));
      float al = expf(-c8[j] * sf);
      float be = sqrtf(1.0f - al * al + 1e-6f);
      float xi = bf2f(i4[j]) + bgi[j];
      float si = 1.0f / (1.0f + expf(-xi));
      float xt = be * si * bf2f(u4[j]);
      hl[j] = al * hl[j] + xt;
      ap[j] *= al;
    }
  }
  size_t ci = ((size_t)c * NB + n) * HID + hb;
  *reinterpret_cast<f32x4*>(&Ac[ci]) = f32x4{ap[0], ap[1], ap[2], ap[3]};
  *reinterpret_cast<f32x4*>(&Bc[ci]) = f32x4{hl[0], hl[1], hl[2], hl[3]};
}

__global__ void scan_phase2(const float* __restrict__ Ac, const float* __restrict__ Bc,
                            float* __restrict__ Carry) {
  int tid = blockIdx.x * blockDim.x + threadIdx.x;  // NB*HID, 128-thread blocks
  int h = tid % HID;
  int n = tid / HID;
  float carry = 0.f;
#pragma unroll 4
  for (int c = 0; c < NC; c++) {
    size_t ci = ((size_t)c * NB + n) * HID + h;
    Carry[ci] = carry;
    carry = Ac[ci] * carry + Bc[ci];
  }
}

__global__ void scan_phase3(const u16* __restrict__ fbuf, const u16* __restrict__ ibuf,
                            const u16* __restrict__ ubuf, const u16* __restrict__ gbuf,
                            const float* __restrict__ fb, const float* __restrict__ bg,
                            const float* __restrict__ Carry, u16* __restrict__ gh) {
  int tid = blockIdx.x * blockDim.x + threadIdx.x;  // NB*H4*NC
  int hb = (tid % H4) * 4;
  int nc = tid / H4;
  int n = nc % NB;
  int c = nc / NB;
  f32x4 fbv = *reinterpret_cast<const f32x4*>(&fb[hb]);
  f32x4 bgf = *reinterpret_cast<const f32x4*>(&bg[hb]);
  f32x4 bgi = *reinterpret_cast<const f32x4*>(&bg[HID + hb]);
  float c8[4], hc[4];
#pragma unroll
  for (int j = 0; j < 4; j++) c8[j] = 8.0f * log1pf(expf(fbv[j]));
  size_t ci = ((size_t)c * NB + n) * HID + hb;
  f32x4 cv = *reinterpret_cast<const f32x4*>(&Carry[ci]);
#pragma unroll
  for (int j = 0; j < 4; j++) hc[j] = cv[j];
  size_t base = ((size_t)n * TT + (size_t)c * CH) * HID + hb;
  for (int t = 0; t < CH; t++) {
    size_t ix = base + (size_t)t * HID;
    u16x4 f4 = *reinterpret_cast<const u16x4*>(&fbuf[ix]);
    u16x4 i4 = *reinterpret_cast<const u16x4*>(&ibuf[ix]);
    u16x4 u4 = *reinterpret_cast<const u16x4*>(&ubuf[ix]);
    u16x4 g4 = *reinterpret_cast<const u16x4*>(&gbuf[ix]);  // already gelu'd
    u16x4 o4;
#pragma unroll
    for (int j = 0; j < 4; j++) {
      float f = bf2f(f4[j]) + bgf[j];
      float sf = 1.0f / (1.0f + expf(-f));
      float al = expf(-c8[j] * sf);
      float be = sqrtf(1.0f - al * al + 1e-6f);
      float xi = bf2f(i4[j]) + bgi[j];
      float si = 1.0f / (1.0f + expf(-xi));
      float xt = be * si * bf2f(u4[j]);
      hc[j] = al * hc[j] + xt;
      o4[j] = f2bf(bf2f(g4[j]) * hc[j]);
    }
    *reinterpret_cast<u16x4*>(&gh[ix]) = o4;
  }
}

// ---------------- launch ----------------
extern "C" void kernel_launch(void* const* d_in, const int* in_sizes, int n_in,
                              void* d_out, int out_size, void* d_ws, size_t ws_size,
                              hipStream_t stream) {
  const float* x  = (const float*)d_in[0];
  const float* Wi = (const float*)d_in[1];
  const float* cw = (const float*)d_in[2];
  const float* cb = (const float*)d_in[3];
  const float* Wg = (const float*)d_in[4];
  const float* bg = (const float*)d_in[5];
  const float* fb = (const float*)d_in[6];
  const float* Wo = (const float*)d_in[7];
  float* out = (float*)d_out;

  const size_t SZ_XBF = (size_t)MROWS * DIM * 2;
  const size_t SZ_WI  = (size_t)2 * HID * DIM * 2;
  const size_t SZ_WG  = (size_t)2 * HID * HID * 2;
  const size_t SZ_WO  = (size_t)DIM * HID * 2;
  const size_t SZ_ACT = (size_t)MROWS * HID * 2;
  const size_t REQUIRED = SZ_XBF + SZ_WI + SZ_WG + SZ_WO + 4 * SZ_ACT;
  if (ws_size < REQUIRED) return;

  char* p = (char*)d_ws;
  auto alloc = [&](size_t bytes) { char* q = p; p += bytes; return q; };
  u16* x_bf   = (u16*)alloc(SZ_XBF);
  u16* Wi_bf  = (u16*)alloc(SZ_WI);
  u16* Wg_bf  = (u16*)alloc(SZ_WG);
  u16* Wo_bf  = (u16*)alloc(SZ_WO);
  u16* u_bf   = (u16*)alloc(SZ_ACT);   // raw u; reused as gh after conv
  u16* uc_bf  = (u16*)alloc(SZ_ACT);   // conv output
  u16* fg0_bf = (u16*)alloc(SZ_ACT);   // forget logits
  u16* fg1_bf = (u16*)alloc(SZ_ACT);   // input-gate logits
  u16* gh_bf  = u_bf;

  // gate (gelu'd) + scan state in d_out; Carry aliases Ac (phase2 reads
  // Ac[ci] before writing Carry[ci] per element -> in-place safe).
  u16* gate_bf = (u16*)d_out;
  float* Ac    = (float*)((char*)d_out + SZ_ACT);
  float* Bc    = Ac + (size_t)NC * NB * HID;
  float* Carry = Ac;

  // fused fp32->bf16 conversions (one launch)
  const int n0 = MROWS * DIM / 4, n1 = 2 * HID * DIM / 4,
            n2 = 2 * HID * HID / 4, n3 = DIM * HID / 4;
  cvt_all<<<(n0 + n1 + n2 + n3 + 255) / 256, 256, 0, stream>>>(
      x, x_bf, n0, Wi, Wi_bf, n1, Wg, Wg_bf, n2, Wo, Wo_bf, n3);

  // gi = x * Wi^T -> gelu(gate) | u    grid 12*64 = 768
  gemm256<2><<<(2 * HID / 256) * (MROWS / 256), 512, 0, stream>>>(
      x_bf, Wi_bf, nullptr, gate_bf, u_bf, MROWS, 2 * HID, DIM, 2 * HID / 256);
  // causal depthwise conv
  conv1d_k<<<(NB * (TT / TC) * H8) / 256, 256, 0, stream>>>(u_bf, cw, cb, uc_bf);
  // fg = uc * Wg^T -> forget | inp
  gemm256<1><<<(2 * HID / 256) * (MROWS / 256), 512, 0, stream>>>(
      uc_bf, Wg_bf, nullptr, fg0_bf, fg1_bf, MROWS, 2 * HID, HID, 2 * HID / 256);
  // RG-LRU scan + gate multiply (NC=256 -> 1536 blocks)
  scan_phase1<<<(NB * H4 * NC) / 256, 256, 0, stream>>>(fg0_bf, fg1_bf, uc_bf, fb, bg, Ac, Bc);
  scan_phase2<<<(NB * HID) / 128, 128, 0, stream>>>(Ac, Bc, Carry);
  scan_phase3<<<(NB * H4 * NC) / 256, 256, 0, stream>>>(fg0_bf, fg1_bf, uc_bf, gate_bf, fb, bg, Carry, gh_bf);
  // out = gh * Wo^T (fp32)   grid 4*64 = 256
  gemm256<0><<<(DIM / 256) * (MROWS / 256), 512, 0, stream>>>(
      gh_bf, Wo_bf, out, nullptr, nullptr, MROWS, DIM, HID, DIM / 256);
}

// Round 17
// 574.241 us; speedup vs baseline: 2.0169x; 2.0169x over previous
//
#include <hip/hip_runtime.h>

#define DIM 1024
#define HID 1536
#define TT 4096
#define NB 4
#define KCONV 4
#define MROWS (NB * TT)  // 16384
#define NC 256           // scan chunks
#define CH (TT / NC)     // 16
#define H8 (HID / 8)     // 192
#define H4 (HID / 4)     // 384
#define TC 16            // conv rows per thread

typedef unsigned short u16;
typedef short bf16x8 __attribute__((ext_vector_type(8)));
typedef u16 u16x4 __attribute__((ext_vector_type(4)));
typedef float f32x4 __attribute__((ext_vector_type(4)));

__device__ __forceinline__ u16 f2bf(float f) {
  union { float f; unsigned u; } v; v.f = f;
  unsigned r = (v.u + 0x7fffu + ((v.u >> 16) & 1u)) >> 16;
  return (u16)r;
}
__device__ __forceinline__ float bf2f(u16 h) {
  union { unsigned u; float f; } v; v.u = ((unsigned)h) << 16;
  return v.f;
}
__device__ __forceinline__ float gelu_exact(float g) {
  return 0.5f * g * (1.0f + erff(g * 0.70710678118f));
}

// ---------------- fused fp32 -> bf16 convert (4 regions, 1 launch) --------
__global__ void cvt_all(const float* __restrict__ s0, u16* __restrict__ d0, int n0,
                        const float* __restrict__ s1, u16* __restrict__ d1, int n1,
                        const float* __restrict__ s2, u16* __restrict__ d2, int n2,
                        const float* __restrict__ s3, u16* __restrict__ d3, int n3) {
  int i = blockIdx.x * blockDim.x + threadIdx.x;  // in float4 units
  const float* s; u16* d; int k;
  if (i < n0) { s = s0; d = d0; k = i; }
  else if (i < n0 + n1) { s = s1; d = d1; k = i - n0; }
  else if (i < n0 + n1 + n2) { s = s2; d = d2; k = i - n0 - n1; }
  else if (i < n0 + n1 + n2 + n3) { s = s3; d = d3; k = i - n0 - n1 - n2; }
  else return;
  float4 v = reinterpret_cast<const float4*>(s)[k];
  ushort4 o;
  o.x = f2bf(v.x); o.y = f2bf(v.y); o.z = f2bf(v.z); o.w = f2bf(v.w);
  reinterpret_cast<ushort4*>(d)[k] = o;
}

#define AS1q __attribute__((address_space(1)))
#define AS3q __attribute__((address_space(3)))
__device__ __forceinline__ void glds16(const u16* g, u16* l) {
  __builtin_amdgcn_global_load_lds((const AS1q void*)g, (AS3q void*)l, 16, 0, 0);
}

// ================= 256x256 bf16 NT GEMM, 4-phase/iter =====================
// R15 (verified): no pre-MFMA barriers, stage-early pinned by sched_barrier.
// R17: WAITV8 deep-pipeline waits in a SINGLE loop body (R16's duplicated
// body caused acc spills: WRITE_SIZE 98->976 MB). Ledger: each read's
// producer-stage is 3 phase-groups old; V8 leaves 2 newest groups in flight.
// Tail: P2-end V4 (drains prev-P4 before P3's buf1/kk0 read), P3-end V0
// (drains P1's stage before P4's buf1/kk1 read).
#define BAR    asm volatile("s_barrier" ::: "memory")
#define WAITV8 asm volatile("s_waitcnt vmcnt(8)" ::: "memory")
#define WAITV4 asm volatile("s_waitcnt vmcnt(4)" ::: "memory")
#define WAITV0 asm volatile("s_waitcnt vmcnt(0)" ::: "memory")
#define SCHED0 __builtin_amdgcn_sched_barrier(0)

template <int EPI>
__global__ __launch_bounds__(512, 2) void gemm256(
    const u16* __restrict__ A, const u16* __restrict__ B,
    float* __restrict__ C, u16* __restrict__ O0, u16* __restrict__ O1,
    int M, int Nn, int K, int gx) {
  __shared__ u16 LA[2][2][8192];
  __shared__ u16 LB[2][2][8192];
  const int tid = threadIdx.x;
  const int l = tid & 63;
  const int wid = tid >> 6;
  const int wr = wid >> 2;
  const int wc = wid & 3;

  // two-level XCD swizzle (R6-verified: FETCH 227->123 MB)
  const int bid = blockIdx.x;
  const int gm8 = (M >> 8) >> 3;
  const int xcd = bid & 7;
  const int idx = bid >> 3;
  const int mg  = idx / (4 * gx);
  const int rem = idx % (4 * gx);
  const int nn  = rem >> 2;
  const int mi  = rem & 3;
  const int tileM = (xcd * gm8 + mg * 4 + mi) * 256;
  const int tileN = nn * 256;

  const int lp = l ^ ((l & 32) >> 4);
  const int srow = lp >> 2;
  const int scol = (lp & 3) * 8;
  const int rdoff = ((l & 15) * 32 + (l >> 4) * 8) ^ ((l & 8) << 1);

  const u16* Abase = A + (size_t)(tileM + wid * 32 + srow) * K + scol;
  const u16* Bbase = B + (size_t)(tileN + wid * 32 + srow) * K + scol;

#define STAGE_A(c, kk, kt) { const u16* g_ = Abase + (size_t)(kt) * 64 + (kk) * 32; \
    glds16(g_, &LA[c][kk][wid * 1024]); glds16(g_ + 16 * (size_t)K, &LA[c][kk][wid * 1024 + 512]); }
#define STAGE_B(c, kk, kt) { const u16* g_ = Bbase + (size_t)(kt) * 64 + (kk) * 32; \
    glds16(g_, &LB[c][kk][wid * 1024]); glds16(g_ + 16 * (size_t)K, &LB[c][kk][wid * 1024 + 512]); }

  f32x4 acc[8][4] = {};
  bf16x8 a[8], b[4];

#define LDB4(c, kk) { _Pragma("unroll") for (int ni = 0; ni < 4; ni++) \
    b[ni] = *(const bf16x8*)&LB[c][kk][(wc * 4 + ni) * 512 + rdoff]; }
#define LDA8(c, kk) { _Pragma("unroll") for (int mi2 = 0; mi2 < 8; mi2++) \
    a[mi2] = *(const bf16x8*)&LA[c][kk][(wr * 8 + mi2) * 512 + rdoff]; }
#define MFMA32 { __builtin_amdgcn_s_setprio(1); \
    _Pragma("unroll") for (int mi2 = 0; mi2 < 8; mi2++) \
    _Pragma("unroll") for (int ni = 0; ni < 4; ni++) \
      acc[mi2][ni] = __builtin_amdgcn_mfma_f32_16x16x32_bf16(a[mi2], b[ni], acc[mi2][ni], 0, 0, 0); \
    __builtin_amdgcn_s_setprio(0); }

  STAGE_A(0, 0, 0); STAGE_B(0, 0, 0);
  STAGE_A(0, 1, 0); STAGE_B(0, 1, 0);
  STAGE_A(1, 0, 1); STAGE_B(1, 0, 1);
  WAITV4; BAR;

  const int NIT = K >> 7;
  for (int i = 0; i < NIT; i++) {
    const int kt = 2 * i;
    const bool nl = (i + 1 < NIT);
    // P1: read buf0/kk0; stage buf1/kk1(kt+1) [always: consumed by P4 this iter]
    LDB4(0, 0); LDA8(0, 0); STAGE_A(1, 1, kt + 1); STAGE_B(1, 1, kt + 1);
    SCHED0; MFMA32; WAITV8; BAR;
    // P2: read buf0/kk1; stage buf0/kk0(kt+2)
    LDB4(0, 1); LDA8(0, 1); if (nl) { STAGE_A(0, 0, kt + 2); STAGE_B(0, 0, kt + 2); }
    SCHED0; MFMA32; if (nl) { WAITV8; } else { WAITV4; } BAR;
    // P3: read buf1/kk0; stage buf0/kk1(kt+2)
    LDB4(1, 0); LDA8(1, 0); if (nl) { STAGE_A(0, 1, kt + 2); STAGE_B(0, 1, kt + 2); }
    SCHED0; MFMA32; if (nl) { WAITV8; } else { WAITV0; } BAR;
    // P4: read buf1/kk1; stage buf1/kk0(kt+3)
    LDB4(1, 1); LDA8(1, 1); if (nl) { STAGE_A(1, 0, kt + 3); STAGE_B(1, 0, kt + 3); }
    SCHED0; MFMA32; if (nl) { WAITV8; } BAR;
  }

  const int r0 = tileM + wr * 128 + (l >> 4) * 4;
  const int c0 = tileN + wc * 64 + (l & 15);
  if (EPI == 0) {
#pragma unroll
    for (int ai = 0; ai < 8; ai++)
#pragma unroll
      for (int ni = 0; ni < 4; ni++)
#pragma unroll
        for (int r = 0; r < 4; r++)
          C[(size_t)(r0 + ai * 16 + r) * Nn + (c0 + ni * 16)] = acc[ai][ni][r];
  } else {
    const bool lo = (tileN < HID);
    u16* dst = lo ? O0 : O1;
    const int cb = lo ? 0 : HID;
#pragma unroll
    for (int ai = 0; ai < 8; ai++)
#pragma unroll
      for (int ni = 0; ni < 4; ni++)
#pragma unroll
        for (int r = 0; r < 4; r++) {
          float v = acc[ai][ni][r];
          if (EPI == 2 && lo) v = gelu_exact(v);
          dst[(size_t)(r0 + ai * 16 + r) * HID + (c0 + ni * 16 - cb)] = f2bf(v);
        }
  }
#undef STAGE_A
#undef STAGE_B
#undef LDB4
#undef LDA8
#undef MFMA32
}

// ---------------- causal depthwise conv1d (K=4) ----------------
__global__ void conv1d_k(const u16* __restrict__ u, const float* __restrict__ w,
                         const float* __restrict__ b, u16* __restrict__ uc) {
  int idx = blockIdx.x * blockDim.x + threadIdx.x;  // NB*(TT/TC)*H8
  int hb = (idx % H8) * 8;
  int rc = idx / H8;
  int t0 = (rc % (TT / TC)) * TC;
  int n  = rc / (TT / TC);

  float wt[KCONV][8], bias[8];
#pragma unroll
  for (int j = 0; j < 8; j++) {
    float4 wj = reinterpret_cast<const float4*>(w)[hb + j];
    wt[0][j] = wj.x; wt[1][j] = wj.y; wt[2][j] = wj.z; wt[3][j] = wj.w;
    bias[j] = b[hb + j];
  }

  const u16* up = u + (size_t)n * TT * HID + hb;
  u16* op = uc + (size_t)n * TT * HID + hb;
  bf16x8 zero;
#pragma unroll
  for (int j = 0; j < 8; j++) zero[j] = 0;
  bf16x8 w0 = (t0 > 0) ? *(const bf16x8*)&up[(size_t)(t0 - 3) * HID] : zero;
  bf16x8 w1 = (t0 > 0) ? *(const bf16x8*)&up[(size_t)(t0 - 2) * HID] : zero;
  bf16x8 w2 = (t0 > 0) ? *(const bf16x8*)&up[(size_t)(t0 - 1) * HID] : zero;
#pragma unroll 4
  for (int t = t0; t < t0 + TC; t++) {
    bf16x8 cur = *(const bf16x8*)&up[(size_t)t * HID];
    bf16x8 o;
#pragma unroll
    for (int j = 0; j < 8; j++) {
      float a = bias[j];
      a += bf2f((u16)w0[j]) * wt[0][j];
      a += bf2f((u16)w1[j]) * wt[1][j];
      a += bf2f((u16)w2[j]) * wt[2][j];
      a += bf2f((u16)cur[j]) * wt[3][j];
      o[j] = (short)f2bf(a);
    }
    *(bf16x8*)&op[(size_t)t * HID] = o;
    w0 = w1; w1 = w2; w2 = cur;
  }
}

// ---------------- RG-LRU scan, chunked 3-phase, 4 ch/thread (R12) ----------
__global__ void scan_phase1(const u16* __restrict__ fbuf, const u16* __restrict__ ibuf,
                            const u16* __restrict__ ubuf, const float* __restrict__ fb,
                            const float* __restrict__ bg,
                            float* __restrict__ Ac, float* __restrict__ Bc) {
  int tid = blockIdx.x * blockDim.x + threadIdx.x;  // NB*H4*NC
  int hb = (tid % H4) * 4;
  int nc = tid / H4;
  int n = nc % NB;
  int c = nc / NB;
  f32x4 fbv = *reinterpret_cast<const f32x4*>(&fb[hb]);
  f32x4 bgf = *reinterpret_cast<const f32x4*>(&bg[hb]);
  f32x4 bgi = *reinterpret_cast<const f32x4*>(&bg[HID + hb]);
  float c8[4], ap[4] = {1.f, 1.f, 1.f, 1.f}, hl[4] = {0.f, 0.f, 0.f, 0.f};
#pragma unroll
  for (int j = 0; j < 4; j++) c8[j] = 8.0f * log1pf(expf(fbv[j]));
  size_t base = ((size_t)n * TT + (size_t)c * CH) * HID + hb;
  for (int t = 0; t < CH; t++) {
    size_t ix = base + (size_t)t * HID;
    u16x4 f4 = *reinterpret_cast<const u16x4*>(&fbuf[ix]);
    u16x4 i4 = *reinterpret_cast<const u16x4*>(&ibuf[ix]);
    u16x4 u4 = *reinterpret_cast<const u16x4*>(&ubuf[ix]);
#pragma unroll
    for (int j = 0; j < 4; j++) {
      float f = bf2f(f4[j]) + bgf[j];
      float sf = 1.0f / (1.0f + expf(-f));
      float al = expf(-c8[j] * sf);
      float be = sqrtf(1.0f - al * al + 1e-6f);
      float xi = bf2f(i4[j]) + bgi[j];
      float si = 1.0f / (1.0f + expf(-xi));
      float xt = be * si * bf2f(u4[j]);
      hl[j] = al * hl[j] + xt;
      ap[j] *= al;
    }
  }
  size_t ci = ((size_t)c * NB + n) * HID + hb;
  *reinterpret_cast<f32x4*>(&Ac[ci]) = f32x4{ap[0], ap[1], ap[2], ap[3]};
  *reinterpret_cast<f32x4*>(&Bc[ci]) = f32x4{hl[0], hl[1], hl[2], hl[3]};
}

__global__ void scan_phase2(const float* __restrict__ Ac, const float* __restrict__ Bc,
                            float* __restrict__ Carry) {
  int tid = blockIdx.x * blockDim.x + threadIdx.x;  // NB*HID, 128-thread blocks
  int h = tid % HID;
  int n = tid / HID;
  float carry = 0.f;
#pragma unroll 4
  for (int c = 0; c < NC; c++) {
    size_t ci = ((size_t)c * NB + n) * HID + h;
    Carry[ci] = carry;
    carry = Ac[ci] * carry + Bc[ci];
  }
}

__global__ void scan_phase3(const u16* __restrict__ fbuf, const u16* __restrict__ ibuf,
                            const u16* __restrict__ ubuf, const u16* __restrict__ gbuf,
                            const float* __restrict__ fb, const float* __restrict__ bg,
                            const float* __restrict__ Carry, u16* __restrict__ gh) {
  int tid = blockIdx.x * blockDim.x + threadIdx.x;  // NB*H4*NC
  int hb = (tid % H4) * 4;
  int nc = tid / H4;
  int n = nc % NB;
  int c = nc / NB;
  f32x4 fbv = *reinterpret_cast<const f32x4*>(&fb[hb]);
  f32x4 bgf = *reinterpret_cast<const f32x4*>(&bg[hb]);
  f32x4 bgi = *reinterpret_cast<const f32x4*>(&bg[HID + hb]);
  float c8[4], hc[4];
#pragma unroll
  for (int j = 0; j < 4; j++) c8[j] = 8.0f * log1pf(expf(fbv[j]));
  size_t ci = ((size_t)c * NB + n) * HID + hb;
  f32x4 cv = *reinterpret_cast<const f32x4*>(&Carry[ci]);
#pragma unroll
  for (int j = 0; j < 4; j++) hc[j] = cv[j];
  size_t base = ((size_t)n * TT + (size_t)c * CH) * HID + hb;
  for (int t = 0; t < CH; t++) {
    size_t ix = base + (size_t)t * HID;
    u16x4 f4 = *reinterpret_cast<const u16x4*>(&fbuf[ix]);
    u16x4 i4 = *reinterpret_cast<const u16x4*>(&ibuf[ix]);
    u16x4 u4 = *reinterpret_cast<const u16x4*>(&ubuf[ix]);
    u16x4 g4 = *reinterpret_cast<const u16x4*>(&gbuf[ix]);  // already gelu'd
    u16x4 o4;
#pragma unroll
    for (int j = 0; j < 4; j++) {
      float f = bf2f(f4[j]) + bgf[j];
      float sf = 1.0f / (1.0f + expf(-f));
      float al = expf(-c8[j] * sf);
      float be = sqrtf(1.0f - al * al + 1e-6f);
      float xi = bf2f(i4[j]) + bgi[j];
      float si = 1.0f / (1.0f + expf(-xi));
      float xt = be * si * bf2f(u4[j]);
      hc[j] = al * hc[j] + xt;
      o4[j] = f2bf(bf2f(g4[j]) * hc[j]);
    }
    *reinterpret_cast<u16x4*>(&gh[ix]) = o4;
  }
}

// ---------------- launch ----------------
extern "C" void kernel_launch(void* const* d_in, const int* in_sizes, int n_in,
                              void* d_out, int out_size, void* d_ws, size_t ws_size,
                              hipStream_t stream) {
  const float* x  = (const float*)d_in[0];
  const float* Wi = (const float*)d_in[1];
  const float* cw = (const float*)d_in[2];
  const float* cb = (const float*)d_in[3];
  const float* Wg = (const float*)d_in[4];
  const float* bg = (const float*)d_in[5];
  const float* fb = (const float*)d_in[6];
  const float* Wo = (const float*)d_in[7];
  float* out = (float*)d_out;

  const size_t SZ_XBF = (size_t)MROWS * DIM * 2;
  const size_t SZ_WI  = (size_t)2 * HID * DIM * 2;
  const size_t SZ_WG  = (size_t)2 * HID * HID * 2;
  const size_t SZ_WO  = (size_t)DIM * HID * 2;
  const size_t SZ_ACT = (size_t)MROWS * HID * 2;
  const size_t REQUIRED = SZ_XBF + SZ_WI + SZ_WG + SZ_WO + 4 * SZ_ACT;
  if (ws_size < REQUIRED) return;

  char* p = (char*)d_ws;
  auto alloc = [&](size_t bytes) { char* q = p; p += bytes; return q; };
  u16* x_bf   = (u16*)alloc(SZ_XBF);
  u16* Wi_bf  = (u16*)alloc(SZ_WI);
  u16* Wg_bf  = (u16*)alloc(SZ_WG);
  u16* Wo_bf  = (u16*)alloc(SZ_WO);
  u16* u_bf   = (u16*)alloc(SZ_ACT);   // raw u; reused as gh after conv
  u16* uc_bf  = (u16*)alloc(SZ_ACT);   // conv output
  u16* fg0_bf = (u16*)alloc(SZ_ACT);   // forget logits
  u16* fg1_bf = (u16*)alloc(SZ_ACT);   // input-gate logits
  u16* gh_bf  = u_bf;

  // gate (gelu'd) + scan state in d_out; Carry aliases Ac (phase2 reads
  // Ac[ci] before writing Carry[ci] per element -> in-place safe).
  u16* gate_bf = (u16*)d_out;
  float* Ac    = (float*)((char*)d_out + SZ_ACT);
  float* Bc    = Ac + (size_t)NC * NB * HID;
  float* Carry = Ac;

  // fused fp32->bf16 conversions (one launch)
  const int n0 = MROWS * DIM / 4, n1 = 2 * HID * DIM / 4,
            n2 = 2 * HID * HID / 4, n3 = DIM * HID / 4;
  cvt_all<<<(n0 + n1 + n2 + n3 + 255) / 256, 256, 0, stream>>>(
      x, x_bf, n0, Wi, Wi_bf, n1, Wg, Wg_bf, n2, Wo, Wo_bf, n3);

  // gi = x * Wi^T -> gelu(gate) | u    grid 12*64 = 768
  gemm256<2><<<(2 * HID / 256) * (MROWS / 256), 512, 0, stream>>>(
      x_bf, Wi_bf, nullptr, gate_bf, u_bf, MROWS, 2 * HID, DIM, 2 * HID / 256);
  // causal depthwise conv
  conv1d_k<<<(NB * (TT / TC) * H8) / 256, 256, 0, stream>>>(u_bf, cw, cb, uc_bf);
  // fg = uc * Wg^T -> forget | inp
  gemm256<1><<<(2 * HID / 256) * (MROWS / 256), 512, 0, stream>>>(
      uc_bf, Wg_bf, nullptr, fg0_bf, fg1_bf, MROWS, 2 * HID, HID, 2 * HID / 256);
  // RG-LRU scan + gate multiply (NC=256 -> 1536 blocks)
  scan_phase1<<<(NB * H4 * NC) / 256, 256, 0, stream>>>(fg0_bf, fg1_bf, uc_bf, fb, bg, Ac, Bc);
  scan_phase2<<<(NB * HID) / 128, 128, 0, stream>>>(Ac, Bc, Carry);
  scan_phase3<<<(NB * H4 * NC) / 256, 256, 0, stream>>>(fg0_bf, fg1_bf, uc_bf, gate_bf, fb, bg, Carry, gh_bf);
  // out = gh * Wo^T (fp32)   grid 4*64 = 256
  gemm256<0><<<(DIM / 256) * (MROWS / 256), 512, 0, stream>>>(
      gh_bf, Wo_bf, out, nullptr, nullptr, MROWS, DIM, HID, DIM / 256);
}